// Round 23
// baseline (356.963 us; speedup 1.0000x reference)
//
#include <hip/hip_runtime.h>
#include <hip/hip_bf16.h>
#include <cmath>

#define BATCH 64
#define SEQ   512
#define EMBED 384
#define HEADS 7
#define HSZ   54
#define FFND  2304
#define NTOK  (BATCH*SEQ)
#define QKVN  1152   // 3*378 padded to 9*128
#define EPS   1e-5f
#define LAM   0.19632593f     // 54^-0.5 * log2(e): q pre-scale -> exp2-domain softmax
#define THR2  11.5415603f     // defer-max threshold 8 * log2(e)

typedef __attribute__((ext_vector_type(8))) short s16x8;
typedef __attribute__((ext_vector_type(4))) float f32x4;

__device__ __forceinline__ ushort f2bf(float f) {
  __hip_bfloat16 h = __float2bfloat16(f);
  return *reinterpret_cast<ushort*>(&h);
}

__device__ __forceinline__ float exp2fast(float f) {
  return __builtin_amdgcn_exp2f(f);   // v_exp_f32: native 2^x
}

__device__ __forceinline__ void gload16(const void* g, void* l) {
  __builtin_amdgcn_global_load_lds((const __attribute__((address_space(1))) void*)g,
                                   (__attribute__((address_space(3))) void*)l, 16, 0, 0);
}

// ---------------- LayerNorm -> bf16 out, one wave per row ----------------
__global__ __launch_bounds__(256) void ln_bf16_kernel(const float* __restrict__ x,
    const float* __restrict__ g, const float* __restrict__ b, ushort* __restrict__ out) {
  int wave = threadIdx.x >> 6, lane = threadIdx.x & 63;
  int row = (blockIdx.x << 2) + wave;
  const float* xr = x + (size_t)row * EMBED;
  float v[6]; float s = 0.f;
#pragma unroll
  for (int i = 0; i < 6; ++i) { v[i] = xr[lane + (i << 6)]; s += v[i]; }
#pragma unroll
  for (int off = 32; off; off >>= 1) s += __shfl_xor(s, off);
  float mu = s * (1.f / EMBED);
  float var = 0.f;
#pragma unroll
  for (int i = 0; i < 6; ++i) { float d = v[i] - mu; var += d * d; }
#pragma unroll
  for (int off = 32; off; off >>= 1) var += __shfl_xor(var, off);
  float rstd = rsqrtf(var * (1.f / EMBED) + EPS);
  ushort* orow = out + (size_t)row * EMBED;
#pragma unroll
  for (int i = 0; i < 6; ++i) {
    int c = lane + (i << 6);
    orow[c] = f2bf((v[i] - mu) * rstd * g[c] + b[c]);
  }
}

// ---------------- merged weight-prep kernel (block-range dispatch) ----------------
__device__ __forceinline__ void convT_body(const float* __restrict__ in,
    ushort* __restrict__ out, int K, int N, int srcK, int srcN,
    int k0, int n0, int tid, float (*t)[33]) {
  int tx = tid & 31, ty = tid >> 5;
#pragma unroll
  for (int i = 0; i < 4; ++i) {
    int r = ty + i * 8;
    int k = k0 + r, n = n0 + tx;
    t[r][tx] = (k < srcK && n < srcN) ? in[(size_t)k * srcN + n] : 0.f;
  }
  __syncthreads();
#pragma unroll
  for (int i = 0; i < 4; ++i) {
    int r = ty + i * 8;
    int n = n0 + r, k = k0 + tx;
    if (n < N && k < K) out[(size_t)n * K + k] = f2bf(t[tx][r]);
  }
}

__global__ __launch_bounds__(256) void prep_all(
    const float* __restrict__ wq, const float* __restrict__ wk, const float* __restrict__ wv,
    const float* __restrict__ bq, const float* __restrict__ bk, const float* __restrict__ bv,
    const float* __restrict__ wo, const float* __restrict__ w1, const float* __restrict__ w2,
    ushort* __restrict__ wqkvt, ushort* __restrict__ wot,
    ushort* __restrict__ w1t, ushort* __restrict__ w2t,
    float* __restrict__ bqkv, ushort* __restrict__ aout) {
  __shared__ float t[32][33];
  int bid = blockIdx.x, tid = threadIdx.x;
  if (bid < 504) {
    int z = bid / 24, rem = bid - z * 24;
    int k0 = (rem >> 1) << 5, hs0 = (rem & 1) << 5;
    int type = z / 7, h = z - type * 7;
    const float* W = (type == 0) ? wq : (type == 1) ? wk : wv;
    float lam = (type == 0) ? LAM : 1.f;
    int tx = tid & 31, ty = tid >> 5;
#pragma unroll
    for (int i = 0; i < 4; ++i) {
      int r = ty + i * 8;
      int k = k0 + r, hs = hs0 + tx;
      t[r][tx] = (hs < HSZ) ? W[((size_t)h * EMBED + k) * HSZ + hs] : 0.f;
    }
    __syncthreads();
#pragma unroll
    for (int i = 0; i < 4; ++i) {
      int r = ty + i * 8;
      int hs = hs0 + r;
      if (hs < HSZ)
        wqkvt[(size_t)(type * 378 + h * HSZ + hs) * EMBED + k0 + tx] = f2bf(t[tx][r] * lam);
    }
  } else if (bid < 531) {
    int idx = (bid - 504) * 256 + tid;
    if (idx < 18 * EMBED) wqkvt[1134 * EMBED + idx] = 0;
    if (idx < QKVN) {
      float bval = 0.f;
      if (idx < 1134) {
        int type = idx / 378, rem = idx - type * 378;
        int h = rem / HSZ, hs = rem - h * HSZ;
        const float* B = (type == 0) ? bq : (type == 1) ? bk : bv;
        bval = B[h * HSZ + hs];
        if (type == 0) bval *= LAM;
      }
      bqkv[idx] = bval;
    }
  } else if (bid < 675) {
    int r = bid - 531;
    convT_body(wo, wot, EMBED, EMBED, 378, EMBED, (r / 12) << 5, (r % 12) << 5, tid, t);
  } else if (bid < 1539) {
    int r = bid - 675;
    convT_body(w1, w1t, EMBED, FFND, EMBED, FFND, (r % 12) << 5, (r / 12) << 5, tid, t);
  } else if (bid < 2403) {
    int r = bid - 1539;
    convT_body(w2, w2t, FFND, EMBED, FFND, EMBED, (r % 72) << 5, (r / 72) << 5, tid, t);
  } else {
    int idx = (bid - 2403) * 256 + tid;
    if (idx < NTOK * 6) {
      int row = idx / 6, c = idx - row * 6;
      aout[(size_t)row * EMBED + 378 + c] = 0;
    }
  }
}

// ---------------- MFMA flash attention (32 KB unified LDS, exp2 softmax) ----------------
__global__ __launch_bounds__(512) void attn_mfma_kernel(const ushort* __restrict__ qkv,
    ushort* __restrict__ o) {
  __shared__ ushort S[16384];
  int tid = threadIdx.x;
  int id = blockIdx.x;
  int xcd = id & 7;
  int sseq = id >> 3;
  int bh = xcd + 8 * (sseq >> 2);
  int qb = 3 - (sseq & 3);
  int b = bh / HEADS, h = bh - b * HEADS;
  int qr0 = qb << 7;
  int ntile = 2 * qb + 2;
  int w = tid >> 6, l = tid & 63;
  int lr = l & 15, lg = l >> 4;
  const ushort* base = qkv + (size_t)b * SEQ * QKVN + h * HSZ;
  const size_t TSTR = (size_t)64 * QKVN * 2;

  int grow = w * 8 + (l >> 3);
  int gc = (l & 7) ^ (l >> 3);
  const char* kg  = (const char*)(base + 378 + (size_t)grow * QKVN + gc * 8);
  const char* qg0 = (const char*)(base + (size_t)(qr0 + grow) * QKVN + gc * 8);
  const char* qg1 = (const char*)(base + (size_t)(qr0 + 64 + grow) * QKVN + gc * 8);
  int vdst[4]; const char* vsrc[4]; bool vpar[4];
#pragma unroll
  for (int i = 0; i < 4; ++i) {
    int e = tid + i * 512;
    int ev = e >> 1, par = e & 1;
    int p = ev / 28, cv = ev - p * 28;
    if (cv < 27 && p < 32) {
      int k0 = 2 * p;
      int s0 = ((k0 >> 5) << 5) | (((k0 >> 2) & 3) << 3) | (((k0 >> 4) & 1) << 2) | (k0 & 3);
      int d = 2 * cv + par;
      vdst[i] = d * 64 + (s0 ^ ((d & 7) << 3));
      vsrc[i] = (const char*)(base + 756 + (size_t)(2 * p + par) * QKVN + 2 * cv);
      vpar[i] = (par != 0);
    } else { vdst[i] = -1; vsrc[i] = (const char*)base; vpar[i] = false; }
  }

  gload16(qg0, (char*)S + 16384 + w * 1024);
  gload16(qg1, (char*)S + 24576 + w * 1024);
  gload16(kg, (char*)S + w * 1024);
  uint uv[4];
#pragma unroll
  for (int i = 0; i < 4; ++i)
    uv[i] = (vdst[i] >= 0) ? *reinterpret_cast<const uint*>(vsrc[i]) : 0u;
  __syncthreads();
  for (int e = tid; e < 640; e += 512) {
    int r = e / 5, which = e - r * 5;
    int idx = (which == 0) ? (r * 64 + ((6 ^ (r & 7)) << 3) + 6)
                           : (r * 64 + ((7 ^ (r & 7)) << 3) + 2 * (which - 1));
    *reinterpret_cast<uint*>(&S[8192 + idx]) = 0;
  }
#pragma unroll
  for (int i = 0; i < 4; ++i) {
    uint u = uv[i]; uint uo = __shfl_xor(u, 1);
    if (vdst[i] >= 0) {
      uint wv2 = vpar[i] ? ((uo >> 16) | (u & 0xffff0000u)) : ((u & 0xffffu) | (uo << 16));
      *reinterpret_cast<uint*>(&S[4096 + vdst[i]]) = wv2;
    }
  }
  __syncthreads();
  int qrow = w * 16 + lr;
  s16x8 qf[2];
  qf[0] = *reinterpret_cast<const s16x8*>(&S[8192 + qrow * 64 + ((8 * lg) ^ ((qrow & 7) << 3))]);
  qf[1] = *reinterpret_cast<const s16x8*>(&S[8192 + qrow * 64 + ((32 + 8 * lg) ^ ((qrow & 7) << 3))]);
  __syncthreads();

  int qglob = qr0 + qrow;
  float mrow = -1e30f, lrow = 0.f;
  f32x4 acc[4];
#pragma unroll
  for (int d = 0; d < 4; ++d) acc[d] = (f32x4){0.f, 0.f, 0.f, 0.f};

  for (int kt = 0; kt < ntile; ++kt) {
    int cur = kt & 1, nxt = cur ^ 1;
    int curo = cur * 8192;
    if (kt + 1 < ntile) {
      kg += TSTR;
      gload16(kg, (char*)S + nxt * 16384 + w * 1024);
#pragma unroll
      for (int i = 0; i < 4; ++i) {
        vsrc[i] += TSTR;
        if (vdst[i] >= 0) uv[i] = *reinterpret_cast<const uint*>(vsrc[i]);
      }
    }
    bool active = (kt * 64) <= (qr0 + w * 16 + 15);
    if (active) {
      bool diag = (kt * 64 + 63) > (qr0 + w * 16);
      f32x4 sacc[4];
      __builtin_amdgcn_s_setprio(1);
#pragma unroll
      for (int kb = 0; kb < 4; ++kb) {
        sacc[kb] = (f32x4){0.f, 0.f, 0.f, 0.f};
#pragma unroll
        for (int h2 = 0; h2 < 2; ++h2) {
          int row = kb * 16 + lr;
          s16x8 kf = *reinterpret_cast<const s16x8*>(
              &S[curo + row * 64 + ((32 * h2 + 8 * lg) ^ ((row & 7) << 3))]);
          sacc[kb] = __builtin_amdgcn_mfma_f32_16x16x32_bf16(kf, qf[h2], sacc[kb], 0, 0, 0);
        }
      }
      __builtin_amdgcn_s_setprio(0);
      float sv[4][4];
      float mt = -1e30f;
#pragma unroll
      for (int kb = 0; kb < 4; ++kb)
#pragma unroll
        for (int r = 0; r < 4; ++r) {
          float s = sacc[kb][r];
          if (diag && (kt * 64 + kb * 16 + 4 * lg + r) > qglob) s = -1e30f;
          sv[kb][r] = s;
          mt = fmaxf(mt, s);
        }
      mt = fmaxf(mt, __shfl_xor(mt, 16));
      mt = fmaxf(mt, __shfl_xor(mt, 32));
      if (!__all(mt - mrow <= THR2)) {
        float mnew = fmaxf(mrow, mt);
        float al = exp2fast(mrow - mnew);
#pragma unroll
        for (int d = 0; d < 4; ++d)
#pragma unroll
          for (int r = 0; r < 4; ++r) acc[d][r] *= al;
        lrow *= al;
        mrow = mnew;
      }
      union { short s[16]; s16x8 v[2]; } pp;
      float lsum = 0.f;
#pragma unroll
      for (int kb = 0; kb < 4; ++kb)
#pragma unroll
        for (int r = 0; r < 4; ++r) {
          float p = exp2fast(sv[kb][r] - mrow);
          lsum += p;
          pp.s[kb * 4 + r] = (short)f2bf(p);
        }
      lrow += lsum;
      __builtin_amdgcn_s_setprio(1);
#pragma unroll
      for (int m = 0; m < 2; ++m)
#pragma unroll
        for (int d = 0; d < 4; ++d) {
          int row = d * 16 + lr;
          s16x8 vf = *reinterpret_cast<const s16x8*>(
              &S[curo + 4096 + row * 64 + ((32 * m + 8 * lg) ^ ((row & 7) << 3))]);
          acc[d] = __builtin_amdgcn_mfma_f32_16x16x32_bf16(vf, pp.v[m], acc[d], 0, 0, 0);
        }
      __builtin_amdgcn_s_setprio(0);
    }
    if (kt + 1 < ntile) {
#pragma unroll
      for (int i = 0; i < 4; ++i) {
        uint u = uv[i]; uint uo = __shfl_xor(u, 1);
        if (vdst[i] >= 0) {
          uint wv2 = vpar[i] ? ((uo >> 16) | (u & 0xffff0000u)) : ((u & 0xffffu) | (uo << 16));
          *reinterpret_cast<uint*>(&S[nxt * 8192 + 4096 + vdst[i]]) = wv2;
        }
      }
      __syncthreads();
    }
  }

  lrow += __shfl_xor(lrow, 16);
  lrow += __shfl_xor(lrow, 32);
  float linv = 1.f / lrow;
  ushort* Olds = S;
#pragma unroll
  for (int d = 0; d < 4; ++d)
#pragma unroll
    for (int r = 0; r < 4; ++r)
      Olds[(d * 16 + 4 * lg + r) * 128 + w * 16 + lr] = f2bf(acc[d][r] * linv);
  __syncthreads();
  for (int e = tid; e < 128 * 27; e += 512) {
    int q = e / 27, c = e - q * 27;
    uint lo = Olds[(2 * c) * 128 + q];
    uint hi = Olds[(2 * c + 1) * 128 + q];
    *reinterpret_cast<uint*>(&o[(size_t)(b * SEQ + qr0 + q) * EMBED + h * HSZ + 2 * c]) =
        lo | (hi << 16);
  }
}

// ---------------- bf16 MFMA GEMM: 128x128 tile, BK=32, 2-phase, 8 waves, 32 KB LDS --------
// 4 blocks/CU = 32 waves/CU (hardware max): 3 other blocks compute during any barrier drain.
// Chunk swizzle c^(row&3) on both staging source and frag reads (64 B rows, b128 floor).
// Wave grid 2x4: wave (wr,wc) owns 64x32 subtile. Decode YTILE-FASTEST.
// MODE 0: bf16(A@B+bias)  MODE 1: bf16(fast_gelu(A@B+bias))  MODE 2: f32(A@B+bias+resid)
template<int KSTEPS, int LDA, int LDB, int MODE, int NY>
__global__ __launch_bounds__(512) void mfma_gemm(
    const char* __restrict__ Ab, const char* __restrict__ Btb,
    const float* __restrict__ bias, const float* __restrict__ resid,
    char* __restrict__ Cb, int ncols) {
  __shared__ ushort sh[16384];   // A dbuf {0,4096}, B dbuf {8192,12288} (ushort idx); 32 KB
  int tid = threadIdx.x;
  int id = blockIdx.x;
  int xcd = id & 7, t = id >> 3;
  int group = t / (4 * NY), rres = t - group * (4 * NY);
  int xi = rres / NY;
  int ytile = rres - xi * NY;
  int tok0 = (xcd * 32 + group * 4 + xi) << 7;
  int col0 = ytile << 7;
  int wv = tid >> 6, l = tid & 63;
  int wr = wv >> 2, wc = wv & 3;
  int lr = l & 15, lg = l >> 4;

  // staging: thread -> row tid>>2 (0..127), phys chunk tid&3; source logical chunk pre-swizzled
  int srow = tid >> 2;
  int schk = (tid & 3) ^ (srow & 3);
  const char* aptr = Ab + (size_t)(tok0 + srow) * LDA + schk * 16;
  const char* bptr = Btb + (size_t)(col0 + srow) * LDB + schk * 16;

  int offA[4], offB[2];
#pragma unroll
  for (int m = 0; m < 4; ++m) {
    int rowa = wr * 64 + m * 16 + lr;
    offA[m] = rowa * 32 + ((lg ^ (rowa & 3)) << 3);
  }
#pragma unroll
  for (int n = 0; n < 2; ++n) {
    int rowb = wc * 32 + n * 16 + lr;
    offB[n] = rowb * 32 + ((lg ^ (rowb & 3)) << 3);
  }

  f32x4 acc[4][2];
#pragma unroll
  for (int m = 0; m < 4; ++m)
#pragma unroll
    for (int n = 0; n < 2; ++n) acc[m][n] = (f32x4){0.f, 0.f, 0.f, 0.f};

  gload16(aptr, (char*)sh + tid * 16);
  gload16(bptr, (char*)sh + 16384 + tid * 16);
  __syncthreads();

  for (int ks = 0; ks < KSTEPS; ++ks) {
    int buf = ks & 1;
    if (ks + 1 < KSTEPS) {
      int nb = buf ^ 1;
      gload16(aptr + (size_t)(ks + 1) * 64, (char*)sh + nb * 8192 + tid * 16);
      gload16(bptr + (size_t)(ks + 1) * 64, (char*)sh + 16384 + nb * 8192 + tid * 16);
    }
    int ao = buf * 4096, bo = 8192 + buf * 4096;
    __builtin_amdgcn_s_setprio(1);
    s16x8 af[4], bfr[2];
#pragma unroll
    for (int m = 0; m < 4; ++m) af[m] = *reinterpret_cast<const s16x8*>(&sh[ao + offA[m]]);
#pragma unroll
    for (int n = 0; n < 2; ++n) bfr[n] = *reinterpret_cast<const s16x8*>(&sh[bo + offB[n]]);
#pragma unroll
    for (int m = 0; m < 4; ++m)
#pragma unroll
      for (int n = 0; n < 2; ++n)
        acc[m][n] = __builtin_amdgcn_mfma_f32_16x16x32_bf16(af[m], bfr[n], acc[m][n], 0, 0, 0);
    __builtin_amdgcn_s_setprio(0);
    if (ks + 1 < KSTEPS) __syncthreads();
  }

  float bn[2];
  int colr = col0 + wc * 32 + lr;
#pragma unroll
  for (int n = 0; n < 2; ++n) bn[n] = bias[colr + n * 16];

  if constexpr (MODE == 2) {
    int tokr = tok0 + wr * 64 + lg * 4;
    float* C = (float*)Cb;
#pragma unroll
    for (int m = 0; m < 4; ++m)
#pragma unroll
      for (int r = 0; r < 4; ++r) {
        size_t rowbase = (size_t)(tokr + m * 16 + r) * ncols;
#pragma unroll
        for (int n = 0; n < 2; ++n) {
          size_t idx = rowbase + colr + n * 16;
          C[idx] = acc[m][n][r] + bn[n] + resid[idx];
        }
      }
  } else {
    __syncthreads();
    // LDS bounce: sh as [128][128] bf16 (16384 ushorts, exact fit)
#pragma unroll
    for (int m = 0; m < 4; ++m)
#pragma unroll
      for (int r = 0; r < 4; ++r) {
        int row = wr * 64 + m * 16 + lg * 4 + r;
        int rmask = ((row >> 2) & 3) << 4;
#pragma unroll
        for (int n = 0; n < 2; ++n) {
          float xg = acc[m][n][r] + bn[n];
          if constexpr (MODE == 1) {
            float u2 = xg * (2.3022082f + 0.10294324f * xg * xg);
            xg = xg * __builtin_amdgcn_rcpf(1.f + exp2fast(-u2));
          }
          int col = wc * 32 + n * 16 + lr;
          sh[row * 128 + (col ^ rmask)] = f2bf(xg);
        }
      }
    __syncthreads();
    ushort* C = (ushort*)Cb;
    for (int e = tid; e < 2048; e += 512) {
      int row = e >> 4;
      int blk = e & 15;
      int pblk = blk ^ (((row >> 2) & 3) << 1);
      uint4 vvv = *reinterpret_cast<const uint4*>(&sh[row * 128 + pblk * 8]);
      *reinterpret_cast<uint4*>(&C[(size_t)(tok0 + row) * ncols + col0 + blk * 8]) = vvv;
    }
  }
}

extern "C" void kernel_launch(void* const* d_in, const int* in_sizes, int n_in,
                              void* d_out, int out_size, void* d_ws, size_t ws_size,
                              hipStream_t stream) {
  const float* x    = (const float*)d_in[0];
  const float* wq   = (const float*)d_in[1];
  const float* bq   = (const float*)d_in[2];
  const float* wk   = (const float*)d_in[3];
  const float* bk   = (const float*)d_in[4];
  const float* wv   = (const float*)d_in[5];
  const float* bv   = (const float*)d_in[6];
  const float* wo   = (const float*)d_in[7];
  const float* bo   = (const float*)d_in[8];
  const float* w1   = (const float*)d_in[9];
  const float* b1   = (const float*)d_in[10];
  const float* w2   = (const float*)d_in[11];
  const float* b2   = (const float*)d_in[12];
  const float* ln1g = (const float*)d_in[13];
  const float* ln1b = (const float*)d_in[14];
  const float* ln2g = (const float*)d_in[15];
  const float* ln2b = (const float*)d_in[16];
  float* out = (float*)d_out;

  char* wsb = (char*)d_ws;
  float*  x1    = (float*)wsb;
  ushort* ffnb  = (ushort*)(wsb + 50331648);
  ushort* hb    = (ushort*)(wsb + 50331648);
  ushort* qkvb  = (ushort*)(wsb + 75497472);
  ushort* aout  = (ushort*)(wsb + 150994944);
  ushort* h2b   = (ushort*)(wsb + 201326592);
  ushort* w1t   = (ushort*)(wsb + 226492416);
  ushort* w2t   = (ushort*)(wsb + 228261888);
  ushort* wqkvt = (ushort*)(wsb + 230031360);
  ushort* wot   = (ushort*)(wsb + 230916096);
  float*  bqkv  = (float*)(wsb + 231211008);

  prep_all<<<3171, 256, 0, stream>>>(wq, wk, wv, bq, bk, bv, wo, w1, w2,
                                     wqkvt, wot, w1t, w2t, bqkv, aout);
  ln_bf16_kernel<<<NTOK / 4, 256, 0, stream>>>(x, ln1g, ln1b, hb);
  mfma_gemm<EMBED / 32, EMBED * 2, EMBED * 2, 0, QKVN / 128>
      <<<256 * (QKVN / 128), 512, 0, stream>>>(
      (const char*)hb, (const char*)wqkvt, bqkv, nullptr, (char*)qkvb, QKVN);
  attn_mfma_kernel<<<BATCH * HEADS * 4, 512, 0, stream>>>(qkvb, aout);
  mfma_gemm<EMBED / 32, EMBED * 2, EMBED * 2, 2, EMBED / 128>
      <<<256 * (EMBED / 128), 512, 0, stream>>>(
      (const char*)aout, (const char*)wot, bo, x, (char*)x1, EMBED);
  ln_bf16_kernel<<<NTOK / 4, 256, 0, stream>>>(x1, ln2g, ln2b, h2b);
  mfma_gemm<EMBED / 32, EMBED * 2, EMBED * 2, 1, FFND / 128>
      <<<256 * (FFND / 128), 512, 0, stream>>>(
      (const char*)h2b, (const char*)w1t, b1, nullptr, (char*)ffnb, FFND);
  mfma_gemm<FFND / 32, FFND * 2, FFND * 2, 2, EMBED / 128>
      <<<256 * (EMBED / 128), 512, 0, stream>>>(
      (const char*)ffnb, (const char*)w2t, b2, x1, (char*)out, EMBED);
}

// Round 24
// 339.233 us; speedup vs baseline: 1.0523x; 1.0523x over previous
//
#include <hip/hip_runtime.h>
#include <hip/hip_bf16.h>
#include <cmath>

#define BATCH 64
#define SEQ   512
#define EMBED 384
#define HEADS 7
#define HSZ   54
#define FFND  2304
#define NTOK  (BATCH*SEQ)
#define QKVN  1152   // 3*378 padded to 9*128
#define EPS   1e-5f
#define LAM   0.19632593f     // 54^-0.5 * log2(e): q pre-scale -> exp2-domain softmax
#define THR2  11.5415603f     // defer-max threshold 8 * log2(e)

typedef __attribute__((ext_vector_type(8))) short s16x8;
typedef __attribute__((ext_vector_type(4))) float f32x4;

__device__ __forceinline__ ushort f2bf(float f) {
  __hip_bfloat16 h = __float2bfloat16(f);
  return *reinterpret_cast<ushort*>(&h);
}

__device__ __forceinline__ float exp2fast(float f) {
  return __builtin_amdgcn_exp2f(f);   // v_exp_f32: native 2^x
}

__device__ __forceinline__ void gload16(const void* g, void* l) {
  __builtin_amdgcn_global_load_lds((const __attribute__((address_space(1))) void*)g,
                                   (__attribute__((address_space(3))) void*)l, 16, 0, 0);
}

// ---------------- LayerNorm -> bf16 out, one wave per row ----------------
__global__ __launch_bounds__(256) void ln_bf16_kernel(const float* __restrict__ x,
    const float* __restrict__ g, const float* __restrict__ b, ushort* __restrict__ out) {
  int wave = threadIdx.x >> 6, lane = threadIdx.x & 63;
  int row = (blockIdx.x << 2) + wave;
  const float* xr = x + (size_t)row * EMBED;
  float v[6]; float s = 0.f;
#pragma unroll
  for (int i = 0; i < 6; ++i) { v[i] = xr[lane + (i << 6)]; s += v[i]; }
#pragma unroll
  for (int off = 32; off; off >>= 1) s += __shfl_xor(s, off);
  float mu = s * (1.f / EMBED);
  float var = 0.f;
#pragma unroll
  for (int i = 0; i < 6; ++i) { float d = v[i] - mu; var += d * d; }
#pragma unroll
  for (int off = 32; off; off >>= 1) var += __shfl_xor(var, off);
  float rstd = rsqrtf(var * (1.f / EMBED) + EPS);
  ushort* orow = out + (size_t)row * EMBED;
#pragma unroll
  for (int i = 0; i < 6; ++i) {
    int c = lane + (i << 6);
    orow[c] = f2bf((v[i] - mu) * rstd * g[c] + b[c]);
  }
}

// ---------------- merged weight-prep kernel (block-range dispatch) ----------------
__device__ __forceinline__ void convT_body(const float* __restrict__ in,
    ushort* __restrict__ out, int K, int N, int srcK, int srcN,
    int k0, int n0, int tid, float (*t)[33]) {
  int tx = tid & 31, ty = tid >> 5;
#pragma unroll
  for (int i = 0; i < 4; ++i) {
    int r = ty + i * 8;
    int k = k0 + r, n = n0 + tx;
    t[r][tx] = (k < srcK && n < srcN) ? in[(size_t)k * srcN + n] : 0.f;
  }
  __syncthreads();
#pragma unroll
  for (int i = 0; i < 4; ++i) {
    int r = ty + i * 8;
    int n = n0 + r, k = k0 + tx;
    if (n < N && k < K) out[(size_t)n * K + k] = f2bf(t[tx][r]);
  }
}

__global__ __launch_bounds__(256) void prep_all(
    const float* __restrict__ wq, const float* __restrict__ wk, const float* __restrict__ wv,
    const float* __restrict__ bq, const float* __restrict__ bk, const float* __restrict__ bv,
    const float* __restrict__ wo, const float* __restrict__ w1, const float* __restrict__ w2,
    ushort* __restrict__ wqkvt, ushort* __restrict__ wot,
    ushort* __restrict__ w1t, ushort* __restrict__ w2t,
    float* __restrict__ bqkv, ushort* __restrict__ aout) {
  __shared__ float t[32][33];
  int bid = blockIdx.x, tid = threadIdx.x;
  if (bid < 504) {
    int z = bid / 24, rem = bid - z * 24;
    int k0 = (rem >> 1) << 5, hs0 = (rem & 1) << 5;
    int type = z / 7, h = z - type * 7;
    const float* W = (type == 0) ? wq : (type == 1) ? wk : wv;
    float lam = (type == 0) ? LAM : 1.f;
    int tx = tid & 31, ty = tid >> 5;
#pragma unroll
    for (int i = 0; i < 4; ++i) {
      int r = ty + i * 8;
      int k = k0 + r, hs = hs0 + tx;
      t[r][tx] = (hs < HSZ) ? W[((size_t)h * EMBED + k) * HSZ + hs] : 0.f;
    }
    __syncthreads();
#pragma unroll
    for (int i = 0; i < 4; ++i) {
      int r = ty + i * 8;
      int hs = hs0 + r;
      if (hs < HSZ)
        wqkvt[(size_t)(type * 378 + h * HSZ + hs) * EMBED + k0 + tx] = f2bf(t[tx][r] * lam);
    }
  } else if (bid < 531) {
    int idx = (bid - 504) * 256 + tid;
    if (idx < 18 * EMBED) wqkvt[1134 * EMBED + idx] = 0;
    if (idx < QKVN) {
      float bval = 0.f;
      if (idx < 1134) {
        int type = idx / 378, rem = idx - type * 378;
        int h = rem / HSZ, hs = rem - h * HSZ;
        const float* B = (type == 0) ? bq : (type == 1) ? bk : bv;
        bval = B[h * HSZ + hs];
        if (type == 0) bval *= LAM;
      }
      bqkv[idx] = bval;
    }
  } else if (bid < 675) {
    int r = bid - 531;
    convT_body(wo, wot, EMBED, EMBED, 378, EMBED, (r / 12) << 5, (r % 12) << 5, tid, t);
  } else if (bid < 1539) {
    int r = bid - 675;
    convT_body(w1, w1t, EMBED, FFND, EMBED, FFND, (r % 12) << 5, (r / 12) << 5, tid, t);
  } else if (bid < 2403) {
    int r = bid - 1539;
    convT_body(w2, w2t, FFND, EMBED, FFND, EMBED, (r % 72) << 5, (r / 72) << 5, tid, t);
  } else {
    int idx = (bid - 2403) * 256 + tid;
    if (idx < NTOK * 6) {
      int row = idx / 6, c = idx - row * 6;
      aout[(size_t)row * EMBED + 378 + c] = 0;
    }
  }
}

// ---------------- MFMA flash attention (32 KB unified LDS, exp2 softmax) ----------------
__global__ __launch_bounds__(512) void attn_mfma_kernel(const ushort* __restrict__ qkv,
    ushort* __restrict__ o) {
  __shared__ ushort S[16384];
  int tid = threadIdx.x;
  int id = blockIdx.x;
  int xcd = id & 7;
  int sseq = id >> 3;
  int bh = xcd + 8 * (sseq >> 2);
  int qb = 3 - (sseq & 3);
  int b = bh / HEADS, h = bh - b * HEADS;
  int qr0 = qb << 7;
  int ntile = 2 * qb + 2;
  int w = tid >> 6, l = tid & 63;
  int lr = l & 15, lg = l >> 4;
  const ushort* base = qkv + (size_t)b * SEQ * QKVN + h * HSZ;
  const size_t TSTR = (size_t)64 * QKVN * 2;

  int grow = w * 8 + (l >> 3);
  int gc = (l & 7) ^ (l >> 3);
  const char* kg  = (const char*)(base + 378 + (size_t)grow * QKVN + gc * 8);
  const char* qg0 = (const char*)(base + (size_t)(qr0 + grow) * QKVN + gc * 8);
  const char* qg1 = (const char*)(base + (size_t)(qr0 + 64 + grow) * QKVN + gc * 8);
  int vdst[4]; const char* vsrc[4]; bool vpar[4];
#pragma unroll
  for (int i = 0; i < 4; ++i) {
    int e = tid + i * 512;
    int ev = e >> 1, par = e & 1;
    int p = ev / 28, cv = ev - p * 28;
    if (cv < 27 && p < 32) {
      int k0 = 2 * p;
      int s0 = ((k0 >> 5) << 5) | (((k0 >> 2) & 3) << 3) | (((k0 >> 4) & 1) << 2) | (k0 & 3);
      int d = 2 * cv + par;
      vdst[i] = d * 64 + (s0 ^ ((d & 7) << 3));
      vsrc[i] = (const char*)(base + 756 + (size_t)(2 * p + par) * QKVN + 2 * cv);
      vpar[i] = (par != 0);
    } else { vdst[i] = -1; vsrc[i] = (const char*)base; vpar[i] = false; }
  }

  gload16(qg0, (char*)S + 16384 + w * 1024);
  gload16(qg1, (char*)S + 24576 + w * 1024);
  gload16(kg, (char*)S + w * 1024);
  uint uv[4];
#pragma unroll
  for (int i = 0; i < 4; ++i)
    uv[i] = (vdst[i] >= 0) ? *reinterpret_cast<const uint*>(vsrc[i]) : 0u;
  __syncthreads();
  for (int e = tid; e < 640; e += 512) {
    int r = e / 5, which = e - r * 5;
    int idx = (which == 0) ? (r * 64 + ((6 ^ (r & 7)) << 3) + 6)
                           : (r * 64 + ((7 ^ (r & 7)) << 3) + 2 * (which - 1));
    *reinterpret_cast<uint*>(&S[8192 + idx]) = 0;
  }
#pragma unroll
  for (int i = 0; i < 4; ++i) {
    uint u = uv[i]; uint uo = __shfl_xor(u, 1);
    if (vdst[i] >= 0) {
      uint wv2 = vpar[i] ? ((uo >> 16) | (u & 0xffff0000u)) : ((u & 0xffffu) | (uo << 16));
      *reinterpret_cast<uint*>(&S[4096 + vdst[i]]) = wv2;
    }
  }
  __syncthreads();
  int qrow = w * 16 + lr;
  s16x8 qf[2];
  qf[0] = *reinterpret_cast<const s16x8*>(&S[8192 + qrow * 64 + ((8 * lg) ^ ((qrow & 7) << 3))]);
  qf[1] = *reinterpret_cast<const s16x8*>(&S[8192 + qrow * 64 + ((32 + 8 * lg) ^ ((qrow & 7) << 3))]);
  __syncthreads();

  int qglob = qr0 + qrow;
  float mrow = -1e30f, lrow = 0.f;
  f32x4 acc[4];
#pragma unroll
  for (int d = 0; d < 4; ++d) acc[d] = (f32x4){0.f, 0.f, 0.f, 0.f};

  for (int kt = 0; kt < ntile; ++kt) {
    int cur = kt & 1, nxt = cur ^ 1;
    int curo = cur * 8192;
    if (kt + 1 < ntile) {
      kg += TSTR;
      gload16(kg, (char*)S + nxt * 16384 + w * 1024);
#pragma unroll
      for (int i = 0; i < 4; ++i) {
        vsrc[i] += TSTR;
        if (vdst[i] >= 0) uv[i] = *reinterpret_cast<const uint*>(vsrc[i]);
      }
    }
    bool active = (kt * 64) <= (qr0 + w * 16 + 15);
    if (active) {
      bool diag = (kt * 64 + 63) > (qr0 + w * 16);
      f32x4 sacc[4];
      __builtin_amdgcn_s_setprio(1);
#pragma unroll
      for (int kb = 0; kb < 4; ++kb) {
        sacc[kb] = (f32x4){0.f, 0.f, 0.f, 0.f};
#pragma unroll
        for (int h2 = 0; h2 < 2; ++h2) {
          int row = kb * 16 + lr;
          s16x8 kf = *reinterpret_cast<const s16x8*>(
              &S[curo + row * 64 + ((32 * h2 + 8 * lg) ^ ((row & 7) << 3))]);
          sacc[kb] = __builtin_amdgcn_mfma_f32_16x16x32_bf16(kf, qf[h2], sacc[kb], 0, 0, 0);
        }
      }
      __builtin_amdgcn_s_setprio(0);
      float sv[4][4];
      float mt = -1e30f;
#pragma unroll
      for (int kb = 0; kb < 4; ++kb)
#pragma unroll
        for (int r = 0; r < 4; ++r) {
          float s = sacc[kb][r];
          if (diag && (kt * 64 + kb * 16 + 4 * lg + r) > qglob) s = -1e30f;
          sv[kb][r] = s;
          mt = fmaxf(mt, s);
        }
      mt = fmaxf(mt, __shfl_xor(mt, 16));
      mt = fmaxf(mt, __shfl_xor(mt, 32));
      if (!__all(mt - mrow <= THR2)) {
        float mnew = fmaxf(mrow, mt);
        float al = exp2fast(mrow - mnew);
#pragma unroll
        for (int d = 0; d < 4; ++d)
#pragma unroll
          for (int r = 0; r < 4; ++r) acc[d][r] *= al;
        lrow *= al;
        mrow = mnew;
      }
      union { short s[16]; s16x8 v[2]; } pp;
      float lsum = 0.f;
#pragma unroll
      for (int kb = 0; kb < 4; ++kb)
#pragma unroll
        for (int r = 0; r < 4; ++r) {
          float p = exp2fast(sv[kb][r] - mrow);
          lsum += p;
          pp.s[kb * 4 + r] = (short)f2bf(p);
        }
      lrow += lsum;
      __builtin_amdgcn_s_setprio(1);
#pragma unroll
      for (int m = 0; m < 2; ++m)
#pragma unroll
        for (int d = 0; d < 4; ++d) {
          int row = d * 16 + lr;
          s16x8 vf = *reinterpret_cast<const s16x8*>(
              &S[curo + 4096 + row * 64 + ((32 * m + 8 * lg) ^ ((row & 7) << 3))]);
          acc[d] = __builtin_amdgcn_mfma_f32_16x16x32_bf16(vf, pp.v[m], acc[d], 0, 0, 0);
        }
      __builtin_amdgcn_s_setprio(0);
    }
    if (kt + 1 < ntile) {
#pragma unroll
      for (int i = 0; i < 4; ++i) {
        uint u = uv[i]; uint uo = __shfl_xor(u, 1);
        if (vdst[i] >= 0) {
          uint wv2 = vpar[i] ? ((uo >> 16) | (u & 0xffff0000u)) : ((u & 0xffffu) | (uo << 16));
          *reinterpret_cast<uint*>(&S[nxt * 8192 + 4096 + vdst[i]]) = wv2;
        }
      }
      __syncthreads();
    }
  }

  lrow += __shfl_xor(lrow, 16);
  lrow += __shfl_xor(lrow, 32);
  float linv = 1.f / lrow;
  ushort* Olds = S;
#pragma unroll
  for (int d = 0; d < 4; ++d)
#pragma unroll
    for (int r = 0; r < 4; ++r)
      Olds[(d * 16 + 4 * lg + r) * 128 + w * 16 + lr] = f2bf(acc[d][r] * linv);
  __syncthreads();
  for (int e = tid; e < 128 * 27; e += 512) {
    int q = e / 27, c = e - q * 27;
    uint lo = Olds[(2 * c) * 128 + q];
    uint hi = Olds[(2 * c + 1) * 128 + q];
    *reinterpret_cast<uint*>(&o[(size_t)(b * SEQ + qr0 + q) * EMBED + h * HSZ + 2 * c]) =
        lo | (hi << 16);
  }
}

// ---------------- bf16 MFMA GEMM: 128x128 tile, BK=64, 2-phase, 8 WAVES (512 thr) ----------
// Wave grid 2x4: wave (wr,wc) owns 64x32 subtile (acc 4x2). 64 KB LDS -> 2 blocks/CU
// = 16 waves/CU. Decode YTILE-FASTEST (A-panel L2-resident).
// MODE 0: bf16(A@B+bias)  MODE 1: bf16(fast_gelu(A@B+bias))  MODE 2: f32(A@B+bias+resid)
template<int KSTEPS, int LDA, int LDB, int MODE, int NY>
__global__ __launch_bounds__(512) void mfma_gemm(
    const char* __restrict__ Ab, const char* __restrict__ Btb,
    const float* __restrict__ bias, const float* __restrict__ resid,
    char* __restrict__ Cb, int ncols) {
  __shared__ ushort sh[32768];
  int tid = threadIdx.x;
  int id = blockIdx.x;
  int xcd = id & 7, t = id >> 3;
  int group = t / (4 * NY), rres = t - group * (4 * NY);
  int xi = rres / NY;
  int ytile = rres - xi * NY;
  int tok0 = (xcd * 32 + group * 4 + xi) << 7;
  int col0 = ytile << 7;
  int wv = tid >> 6, l = tid & 63;
  int wr = wv >> 2, wc = wv & 3;
  int lr = l & 15, lg = l >> 4;

  const char* aptr[2]; const char* bptr[2];
#pragma unroll
  for (int is = 0; is < 2; ++is) {
    int i = is * 512 + tid;
    int row = i >> 3;
    int boff = (i & 7) << 4;
    int sw = boff ^ ((row & 7) << 4);
    aptr[is] = Ab + (size_t)(tok0 + row) * LDA + sw;
    bptr[is] = Btb + (size_t)(col0 + row) * LDB + sw;
  }

  int offA[2][4], offB[2][2];
#pragma unroll
  for (int m = 0; m < 4; ++m) {
    int rowa = wr * 64 + m * 16 + lr;
    int sa = (rowa & 7) << 4;
#pragma unroll
    for (int kk = 0; kk < 2; ++kk) {
      int kb = kk * 64 + lg * 16;
      offA[kk][m] = (rowa * 128 + (kb ^ sa)) >> 1;
    }
  }
#pragma unroll
  for (int n = 0; n < 2; ++n) {
    int rowb = wc * 32 + n * 16 + lr;
    int sb = (rowb & 7) << 4;
#pragma unroll
    for (int kk = 0; kk < 2; ++kk) {
      int kb = kk * 64 + lg * 16;
      offB[kk][n] = (rowb * 128 + (kb ^ sb)) >> 1;
    }
  }

  f32x4 acc[4][2];
#pragma unroll
  for (int m = 0; m < 4; ++m)
#pragma unroll
    for (int n = 0; n < 2; ++n) acc[m][n] = (f32x4){0.f, 0.f, 0.f, 0.f};

#pragma unroll
  for (int is = 0; is < 2; ++is) {
    gload16(aptr[is], (char*)sh + (is * 512 + tid) * 16);
    gload16(bptr[is], (char*)sh + 32768 + (is * 512 + tid) * 16);
  }
  __syncthreads();

  for (int ks = 0; ks < KSTEPS; ++ks) {
    int buf = ks & 1;
    if (ks + 1 < KSTEPS) {
      int nb = buf ^ 1;
#pragma unroll
      for (int is = 0; is < 2; ++is) {
        gload16(aptr[is] + (size_t)(ks + 1) * 128, (char*)sh + nb * 16384 + (is * 512 + tid) * 16);
        gload16(bptr[is] + (size_t)(ks + 1) * 128, (char*)sh + 32768 + nb * 16384 + (is * 512 + tid) * 16);
      }
    }
    int ao = buf * 8192, bo = 16384 + buf * 8192;
    __builtin_amdgcn_s_setprio(1);
#pragma unroll
    for (int kk = 0; kk < 2; ++kk) {
      s16x8 af[4], bfr[2];
#pragma unroll
      for (int m = 0; m < 4; ++m) af[m] = *reinterpret_cast<const s16x8*>(&sh[ao + offA[kk][m]]);
#pragma unroll
      for (int n = 0; n < 2; ++n) bfr[n] = *reinterpret_cast<const s16x8*>(&sh[bo + offB[kk][n]]);
#pragma unroll
      for (int m = 0; m < 4; ++m)
#pragma unroll
        for (int n = 0; n < 2; ++n)
          acc[m][n] = __builtin_amdgcn_mfma_f32_16x16x32_bf16(af[m], bfr[n], acc[m][n], 0, 0, 0);
    }
    __builtin_amdgcn_s_setprio(0);
    if (ks + 1 < KSTEPS) __syncthreads();
  }

  float bn[2];
  int colr = col0 + wc * 32 + lr;
#pragma unroll
  for (int n = 0; n < 2; ++n) bn[n] = bias[colr + n * 16];

  if constexpr (MODE == 2) {
    int tokr = tok0 + wr * 64 + lg * 4;
    float* C = (float*)Cb;
#pragma unroll
    for (int m = 0; m < 4; ++m)
#pragma unroll
      for (int r = 0; r < 4; ++r) {
        size_t rowbase = (size_t)(tokr + m * 16 + r) * ncols;
#pragma unroll
        for (int n = 0; n < 2; ++n) {
          size_t idx = rowbase + colr + n * 16;
          C[idx] = acc[m][n][r] + bn[n] + resid[idx];
        }
      }
  } else {
    __syncthreads();
#pragma unroll
    for (int m = 0; m < 4; ++m)
#pragma unroll
      for (int r = 0; r < 4; ++r) {
        int row = wr * 64 + m * 16 + lg * 4 + r;
        int rmask = ((row >> 2) & 3) << 4;
#pragma unroll
        for (int n = 0; n < 2; ++n) {
          float xg = acc[m][n][r] + bn[n];
          if constexpr (MODE == 1) {
            float u2 = xg * (2.3022082f + 0.10294324f * xg * xg);
            xg = xg * __builtin_amdgcn_rcpf(1.f + exp2fast(-u2));
          }
          int col = wc * 32 + n * 16 + lr;
          sh[row * 128 + (col ^ rmask)] = f2bf(xg);
        }
      }
    __syncthreads();
    ushort* C = (ushort*)Cb;
    for (int e = tid; e < 2048; e += 512) {
      int row = e >> 4;
      int blk = e & 15;
      int pblk = blk ^ (((row >> 2) & 3) << 1);
      uint4 vvv = *reinterpret_cast<const uint4*>(&sh[row * 128 + pblk * 8]);
      *reinterpret_cast<uint4*>(&C[(size_t)(tok0 + row) * ncols + col0 + blk * 8]) = vvv;
    }
  }
}

extern "C" void kernel_launch(void* const* d_in, const int* in_sizes, int n_in,
                              void* d_out, int out_size, void* d_ws, size_t ws_size,
                              hipStream_t stream) {
  const float* x    = (const float*)d_in[0];
  const float* wq   = (const float*)d_in[1];
  const float* bq   = (const float*)d_in[2];
  const float* wk   = (const float*)d_in[3];
  const float* bk   = (const float*)d_in[4];
  const float* wv   = (const float*)d_in[5];
  const float* bv   = (const float*)d_in[6];
  const float* wo   = (const float*)d_in[7];
  const float* bo   = (const float*)d_in[8];
  const float* w1   = (const float*)d_in[9];
  const float* b1   = (const float*)d_in[10];
  const float* w2   = (const float*)d_in[11];
  const float* b2   = (const float*)d_in[12];
  const float* ln1g = (const float*)d_in[13];
  const float* ln1b = (const float*)d_in[14];
  const float* ln2g = (const float*)d_in[15];
  const float* ln2b = (const float*)d_in[16];
  float* out = (float*)d_out;

  char* wsb = (char*)d_ws;
  float*  x1    = (float*)wsb;
  ushort* ffnb  = (ushort*)(wsb + 50331648);
  ushort* hb    = (ushort*)(wsb + 50331648);
  ushort* qkvb  = (ushort*)(wsb + 75497472);
  ushort* aout  = (ushort*)(wsb + 150994944);
  ushort* h2b   = (ushort*)(wsb + 201326592);
  ushort* w1t   = (ushort*)(wsb + 226492416);
  ushort* w2t   = (ushort*)(wsb + 228261888);
  ushort* wqkvt = (ushort*)(wsb + 230031360);
  ushort* wot   = (ushort*)(wsb + 230916096);
  float*  bqkv  = (float*)(wsb + 231211008);

  prep_all<<<3171, 256, 0, stream>>>(wq, wk, wv, bq, bk, bv, wo, w1, w2,
                                     wqkvt, wot, w1t, w2t, bqkv, aout);
  ln_bf16_kernel<<<NTOK / 4, 256, 0, stream>>>(x, ln1g, ln1b, hb);
  mfma_gemm<EMBED / 64, EMBED * 2, EMBED * 2, 0, QKVN / 128>
      <<<256 * (QKVN / 128), 512, 0, stream>>>(
      (const char*)hb, (const char*)wqkvt, bqkv, nullptr, (char*)qkvb, QKVN);
  attn_mfma_kernel<<<BATCH * HEADS * 4, 512, 0, stream>>>(qkvb, aout);
  mfma_gemm<EMBED / 64, EMBED * 2, EMBED * 2, 2, EMBED / 128>
      <<<256 * (EMBED / 128), 512, 0, stream>>>(
      (const char*)aout, (const char*)wot, bo, x, (char*)x1, EMBED);
  ln_bf16_kernel<<<NTOK / 4, 256, 0, stream>>>(x1, ln2g, ln2b, h2b);
  mfma_gemm<EMBED / 64, EMBED * 2, EMBED * 2, 1, FFND / 128>
      <<<256 * (FFND / 128), 512, 0, stream>>>(
      (const char*)h2b, (const char*)w1t, b1, nullptr, (char*)ffnb, FFND);
  mfma_gemm<FFND / 64, FFND * 2, FFND * 2, 2, EMBED / 128>
      <<<256 * (EMBED / 128), 512, 0, stream>>>(
      (const char*)ffnb, (const char*)w2t, b2, x1, (char*)out, EMBED);
}